// Round 19
// baseline (214.988 us; speedup 1.0000x reference)
//
#include <hip/hip_runtime.h>
#include <hip/hip_bf16.h>

typedef __hip_bfloat16 bf16;
typedef __attribute__((ext_vector_type(8))) short short8;
typedef __attribute__((ext_vector_type(4))) float f32x4;
typedef __attribute__((ext_vector_type(16))) float f32x16;

#define B_    4
#define CIN   32
#define HH    256
#define WW    256
#define C1    384
#define NPIX  65536
#define CMID  128
#define COUT  32
#define PW    258
#define VROW  16512   // shorts per padded vt row: 8g * 258col * 8ch

static __device__ __forceinline__ float u2f(unsigned short u) {
    unsigned int x = ((unsigned int)u) << 16;
    return __uint_as_float(x);
}
static __device__ __forceinline__ unsigned short f2u(float f) {
    bf16 h = __float2bfloat16(f);
    return __builtin_bit_cast(unsigned short, h);
}
static __device__ __forceinline__ unsigned int pk2(float lo, float hi) {
    return (unsigned int)f2u(lo) | ((unsigned int)f2u(hi) << 16);
}
static __device__ __forceinline__ void gload16(const void* src, void* dst) {
    __builtin_amdgcn_global_load_lds(
        (const __attribute__((address_space(1))) void*)src,
        (__attribute__((address_space(3))) void*)dst, 16, 0, 0);
}

// ---- w1(384,32,3,3) fp32 -> w1t[tap][cihi4][co384][8] bf16 ----
__global__ __launch_bounds__(256) void k_w1t(const float* __restrict__ w1, short* __restrict__ w1t) {
    const int tap = blockIdx.x;
    for (int i = threadIdx.x; i < 384 * 32; i += 256) {
        int co = i >> 5, cij = i & 31;
        w1t[((size_t)(tap * 4 + (cij >> 3)) * 384 + co) * 8 + (cij & 7)] =
            (short)f2u(w1[(size_t)i * 9 + tap]);
    }
}

// ---- x -> xt2[bl][row][cihi4][col PW][8ch] bf16, zero-padded ----
__global__ __launch_bounds__(256) void k_xt2(const float* __restrict__ x,
                                             unsigned short* __restrict__ xt2, int b0) {
    const int row = blockIdx.x, bl = blockIdx.y, b = b0 + bl;
    const int tx = threadIdx.x;
    unsigned short* rbase = xt2 + (size_t)(bl * PW + row) * 4 * PW * 8;
    const uint4 z = make_uint4(0u, 0u, 0u, 0u);
    if (row == 0 || row == PW - 1) {
        for (int i = tx; i < 4 * PW; i += 256) ((uint4*)rbase)[i] = z;
        return;
    }
    if (tx < 2) {
        int c = tx ? (PW - 1) : 0;
#pragma unroll
        for (int ch = 0; ch < 4; ch++)
            *(uint4*)(rbase + ((size_t)ch * PW + c) * 8) = z;
    }
    const int col = tx + 1;
    const size_t px = (size_t)(row - 1) * WW + tx;
    unsigned int pk[16];
#pragma unroll
    for (int c2 = 0; c2 < 16; c2++) {
        float v0 = x[((size_t)b * CIN + 2 * c2) * NPIX + px];
        float v1 = x[((size_t)b * CIN + 2 * c2 + 1) * NPIX + px];
        pk[c2] = pk2(v0, v1);
    }
#pragma unroll
    for (int ch = 0; ch < 4; ch++)
        *(uint4*)(rbase + ((size_t)ch * PW + col) * 8) =
            make_uint4(pk[ch * 4], pk[ch * 4 + 1], pk[ch * 4 + 2], pk[ch * 4 + 3]);
}

// ---- zero vt borders ----
__global__ __launch_bounds__(256) void k_bordv(unsigned short* __restrict__ vt) {
    const int row = blockIdx.x, bp = blockIdx.y, tx = threadIdx.x;
    unsigned short* base = vt + ((size_t)bp * PW + row) * VROW;
    const uint4 z = make_uint4(0u, 0u, 0u, 0u);
    if (row == 0 || row == PW - 1) {
        for (int i = tx; i < VROW / 8; i += 256) ((uint4*)base)[i] = z;
    } else if (tx < 16) {
        int g = tx >> 1, c = (tx & 1) * (PW - 1);
        *(uint4*)(base + ((size_t)g * PW + c) * 8) = z;
    }
}

// ---- conv1 FUSED, double-buffered epilogue tile (r16 structure) + setprio ----
// LDS: xs 25344 + 2*17408 = 60160 B -> 2 blocks/CU
__global__ __launch_bounds__(256, 2) void k_conv1(
    const unsigned short* __restrict__ xt2, const short* __restrict__ w1t,
    const float* __restrict__ b1, unsigned short* __restrict__ vt,
    unsigned short* __restrict__ pw, float* __restrict__ ps, int nb)
{
    const int nblk = 512 * nb;
    const int m = ((int)blockIdx.x & 7) * (nblk >> 3) + ((int)blockIdx.x >> 3);
    const int chunk = m & 1;
    const int y   = (m >> 1) & 255;
    const int bl  = m >> 9;
    const int px0 = chunk * 128;
    const int cid = bl * 512 + y * 2 + chunk;
    const int tx  = threadIdx.x;
    const int wv  = tx >> 6, l = tx & 63;
    const int lhi = l >> 4, llo = l & 15;

    __shared__ short xs[12 * 132 * 8];
    union obuf {
        short os[64][136];
        short ost[128][66];
        short osw[4][32][32];
    };
    __shared__ obuf ou2[2];

#pragma unroll
    for (int i = 0; i < 3; i++) {
        int p = wv * 3 + i;
        int r = p >> 2, ch = p & 3;
        const char* src = (const char*)xt2 +
            (((size_t)(bl * PW) + y + r) * 4 + ch) * (PW * 16) + (size_t)px0 * 16 + (size_t)l * 16;
        char* dst = (char*)xs + p * 2112;
        gload16(src, dst);
        gload16(src + 1024, dst + 1024);
        if (l < 2) gload16(src + 2048, dst + 2048);
    }
    __syncthreads();

    const short* wbase = w1t + ((size_t)lhi * 384 + llo) * 8;

    short8 qa[2][4];
    f32x4 wacc[2][2];
#pragma unroll
    for (int dt = 0; dt < 2; dt++)
#pragma unroll
        for (int et = 0; et < 2; et++) wacc[dt][et] = (f32x4){0.f, 0.f, 0.f, 0.f};
    float se0 = 0.f, se1 = 0.f;

#pragma unroll
    for (int cog = 0; cog < 6; cog++) {
        const int co0 = cog * 64;
        const int p   = cog & 1;

        f32x4 acc[2][4];
#pragma unroll
        for (int t = 0; t < 2; t++)
#pragma unroll
            for (int mc = 0; mc < 4; mc++) acc[t][mc] = (f32x4){0.f, 0.f, 0.f, 0.f};

        short8 a[4], an[4];
#pragma unroll
        for (int mc = 0; mc < 4; mc++)
            an[mc] = *(const short8*)(wbase + ((size_t)co0 + mc * 16) * 8);
        __builtin_amdgcn_s_setprio(1);
#pragma unroll
        for (int tap = 0; tap < 9; tap++) {
            const int dy = tap / 3, dx = tap % 3;
#pragma unroll
            for (int mc = 0; mc < 4; mc++) a[mc] = an[mc];
            if (tap < 8) {
#pragma unroll
                for (int mc = 0; mc < 4; mc++)
                    an[mc] = *(const short8*)(wbase +
                        ((size_t)(tap + 1) * 4 * 384 + co0 + mc * 16) * 8);
            }
#pragma unroll
            for (int t = 0; t < 2; t++) {
                short8 bfr = *(const short8*)&xs[(((dy * 4 + lhi) * 132) + (wv * 32 + t * 16 + llo + dx)) * 8];
#pragma unroll
                for (int mc = 0; mc < 4; mc++)
                    acc[t][mc] = __builtin_amdgcn_mfma_f32_16x16x32_bf16(a[mc], bfr, acc[t][mc], 0, 0, 0);
            }
        }
        __builtin_amdgcn_s_setprio(0);

        float bias[4][4];
#pragma unroll
        for (int mc = 0; mc < 4; mc++)
#pragma unroll
            for (int r = 0; r < 4; r++)
                bias[mc][r] = b1[co0 + mc * 16 + lhi * 4 + r];

        if (cog < 4) {     // q,k: channel-major staging (alternating buffer)
#pragma unroll
            for (int t = 0; t < 2; t++)
#pragma unroll
                for (int mc = 0; mc < 4; mc++)
#pragma unroll
                    for (int r = 0; r < 4; r++)
                        ou2[p].os[mc * 16 + lhi * 4 + r][wv * 32 + t * 16 + llo] =
                            (short)f2u(acc[t][mc][r] + bias[mc][r]);
        } else {           // v: transposed [px][ch] staging
#pragma unroll
            for (int t = 0; t < 2; t++)
#pragma unroll
                for (int mc = 0; mc < 4; mc++)
#pragma unroll
                    for (int r = 0; r < 4; r++)
                        ou2[p].ost[wv * 32 + t * 16 + llo][mc * 16 + lhi * 4 + r] =
                            (short)f2u(acc[t][mc][r] + bias[mc][r]);
        }
        __syncthreads();   // ou2[p] visible (single barrier per cog)

        if (cog < 2) {
            if ((wv >> 1) == cog) {
                const int chb = (wv & 1) * 32;
#pragma unroll
                for (int dt = 0; dt < 2; dt++)
#pragma unroll
                    for (int ks = 0; ks < 4; ks++)
                        qa[dt][ks] = *(const short8*)&ou2[p].os[chb + dt * 16 + llo][ks * 32 + lhi * 8];
            }
        } else if (cog < 4) {
            if ((wv >> 1) == cog - 2) {
                const int chb = (wv & 1) * 32;
#pragma unroll
                for (int et = 0; et < 2; et++)
#pragma unroll
                    for (int ks = 0; ks < 4; ks++) {
                        short8 kf = *(const short8*)&ou2[p].os[chb + et * 16 + llo][ks * 32 + lhi * 8];
                        short8 pf;
#pragma unroll
                        for (int j = 0; j < 8; j++) {
                            float ef = __expf(u2f((unsigned short)kf[j]));
                            if (et == 0) se0 += ef; else se1 += ef;
                            pf[j] = (short)f2u(ef);
                        }
#pragma unroll
                        for (int dt = 0; dt < 2; dt++)
                            wacc[dt][et] = __builtin_amdgcn_mfma_f32_16x16x32_bf16(
                                qa[dt][ks], pf, wacc[dt][et], 0, 0, 0);
                    }
            }
        } else {
            const int plane = cog - 4;
            unsigned short* rowb = vt + ((size_t)(bl * 2 + plane) * PW + 1 + y) * VROW;
#pragma unroll
            for (int i = 0; i < 4; i++) {
                int u = i * 256 + tx;
                int g = u >> 7, px = u & 127;
                uint4 v = *(const uint4*)&ou2[p].ost[px][g * 8];
                *(uint4*)(rowb + ((size_t)g * PW + 1 + px0 + px) * 8) = v;
            }
        }
    }

    se0 += __shfl_xor(se0, 16); se0 += __shfl_xor(se0, 32);
    se1 += __shfl_xor(se1, 16); se1 += __shfl_xor(se1, 32);
    if (l < 16) {
        ps[(size_t)cid * 128 + wv * 32 + llo]      = se0;
        ps[(size_t)cid * 128 + wv * 32 + 16 + llo] = se1;
    }

    // weights epilogue into ou2[0] (cog4's readers finished before cog5's barrier)
#pragma unroll
    for (int dt = 0; dt < 2; dt++)
#pragma unroll
        for (int et = 0; et < 2; et++)
#pragma unroll
            for (int r = 0; r < 4; r++)
                ou2[0].osw[wv][dt * 16 + lhi * 4 + r][et * 16 + llo] = (short)f2u(wacc[dt][et][r]);
    __syncthreads();

    {
        unsigned short* pwp = pw + (size_t)cid * 4096;
        const unsigned short* osf = (const unsigned short*)&ou2[0];
#pragma unroll
        for (int p2 = 0; p2 < 2; p2++)
            *(uint4*)(pwp + p2 * 2048 + tx * 8) = *(const uint4*)(osf + p2 * 2048 + tx * 8);
    }
}

// ---- reduce partials over 512 chunks (pw bf16), unrolled for MLP ----
__global__ __launch_bounds__(256) void k_wred(
    const unsigned short* __restrict__ pw, const float* __restrict__ ps,
    float* __restrict__ wts, int b0)
{
    const int bh = blockIdx.x;
    const int jq = blockIdx.y;
    const int bl = bh >> 2, h = bh & 3;
    const int tx = threadIdx.x;
    __shared__ float rinvs[32];
    if (tx < 32) {
        float s = 0.f;
        const float* pp = ps + (size_t)bl * 512 * 128 + h * 32 + tx;
#pragma unroll 8
        for (int c = 0; c < 512; c++) s += pp[(size_t)c * 128];
        rinvs[tx] = 1.f / s;
    }
    __syncthreads();
    const int i = jq * 256 + tx;
    const unsigned short* pwp = pw + (size_t)bl * 512 * 4096 + h * 1024 + i;
    float s = 0.f;
#pragma unroll 8
    for (int c = 0; c < 512; c++) s += u2f(pwp[(size_t)c * 4096]);
    wts[(size_t)(b0 * 4 + bh) * 1024 + i] = s * rinvs[i & 31];
}

// ---- fold W into w2: w2te[bl][tap][cvhi16][co32][8] bf16 ----
__global__ __launch_bounds__(256) void k_w2e(
    const float* __restrict__ w2, const float* __restrict__ wts,
    short* __restrict__ w2te, int b0)
{
    const int bl = blockIdx.x, tap = blockIdx.y;
    const int tx = threadIdx.x;
    __shared__ float Wsh[4096];
    __shared__ float w2sh[4096];
    for (int i = tx; i < 4096; i += 256) {
        Wsh[i]  = wts[(size_t)(b0 + bl) * 4096 + i];
        w2sh[i] = w2[(size_t)i * 9 + tap];
    }
    __syncthreads();
#pragma unroll
    for (int rep = 0; rep < 16; rep++) {
        int o = rep * 256 + tx;
        int cv = o >> 5, co = o & 31;
        int h = cv >> 5, d = cv & 31;
        const float* wp = &w2sh[co * 128 + 32 * h];
        const float* Wp = &Wsh[h * 1024 + d * 32];
        float s = 0.f;
#pragma unroll
        for (int e = 0; e < 32; e++) s += wp[e] * Wp[e];
        w2te[((((size_t)bl * 9 + tap) * 16 + (cv >> 3)) * 32 + co) * 8 + (cv & 7)] =
            (short)f2u(s);
    }
}

// ---- conv2e: prefetch-pipelined implicit GEMM (double-buffered xs) + setprio ----
__global__ __launch_bounds__(256, 2) void k_conv2e(
    const unsigned short* __restrict__ vt, const short* __restrict__ w2te,
    const float* __restrict__ b2, float* __restrict__ out, int b0, int nb)
{
    const int nblk = 512 * nb;
    const int m = ((int)blockIdx.x & 7) * (nblk >> 3) + ((int)blockIdx.x >> 3);
    const int chunk = m & 1;
    const int y   = (m >> 1) & 255;
    const int bl  = m >> 9;
    const int px0 = chunk * 128;
    const int bb  = b0 + bl;
    const int tx  = threadIdx.x;
    const int wv  = tx >> 6, l = tx & 63;
    const int lhi = l >> 4, llo = l & 15;

    __shared__ short xs2[2][12 * 132 * 8];
    __shared__ float osf[32][132];

    const short* w2b = w2te + (size_t)bl * 9 * 16 * 32 * 8;

    float bias[2][4];
#pragma unroll
    for (int mm = 0; mm < 2; mm++)
#pragma unroll
        for (int r = 0; r < 4; r++)
            bias[mm][r] = b2[mm * 16 + lhi * 4 + r];

    f32x4 acc[2][2];
#pragma unroll
    for (int t = 0; t < 2; t++)
#pragma unroll
        for (int mm = 0; mm < 2; mm++) acc[t][mm] = (f32x4){0.f, 0.f, 0.f, 0.f};

#pragma unroll
    for (int i = 0; i < 3; i++) {
        int p = wv * 3 + i;
        int r = p >> 2, sg = p & 3;
        const char* src = (const char*)vt +
            (((size_t)(bl * 2 + 0) * PW + y + r) * VROW
             + ((size_t)(0 * 4 + sg) * PW + px0) * 8) * 2 + (size_t)l * 16;
        char* dst = (char*)xs2[0] + p * 2112;
        gload16(src, dst);
        gload16(src + 1024, dst + 1024);
        if (l < 2) gload16(src + 2048, dst + 2048);
    }

#pragma unroll
    for (int cc = 0; cc < 4; cc++) {
        __syncthreads();

        if (cc < 3) {
            const int nplane = (cc + 1) >> 1, nghalf = (cc + 1) & 1;
#pragma unroll
            for (int i = 0; i < 3; i++) {
                int p = wv * 3 + i;
                int r = p >> 2, sg = p & 3;
                const char* src = (const char*)vt +
                    (((size_t)(bl * 2 + nplane) * PW + y + r) * VROW
                     + ((size_t)(nghalf * 4 + sg) * PW + px0) * 8) * 2 + (size_t)l * 16;
                char* dst = (char*)xs2[(cc + 1) & 1] + p * 2112;
                gload16(src, dst);
                gload16(src + 1024, dst + 1024);
                if (l < 2) gload16(src + 2048, dst + 2048);
            }
        }

        const short* xsc = xs2[cc & 1];
        short8 a[2], an[2];
#pragma unroll
        for (int mm = 0; mm < 2; mm++)
            an[mm] = *(const short8*)(w2b + ((size_t)(cc * 4 + lhi) * 32 + mm * 16 + llo) * 8);
        __builtin_amdgcn_s_setprio(1);
#pragma unroll
        for (int tap = 0; tap < 9; tap++) {
            const int dy = tap / 3, dx = tap % 3;
#pragma unroll
            for (int mm = 0; mm < 2; mm++) a[mm] = an[mm];
            if (tap < 8) {
#pragma unroll
                for (int mm = 0; mm < 2; mm++)
                    an[mm] = *(const short8*)(w2b +
                        ((size_t)((tap + 1) * 16 + cc * 4 + lhi) * 32 + mm * 16 + llo) * 8);
            }
#pragma unroll
            for (int t = 0; t < 2; t++) {
                short8 bfr = *(const short8*)&xsc[(((dy * 4 + lhi) * 132) + (wv * 32 + t * 16 + llo + dx)) * 8];
#pragma unroll
                for (int mm = 0; mm < 2; mm++)
                    acc[t][mm] = __builtin_amdgcn_mfma_f32_16x16x32_bf16(a[mm], bfr, acc[t][mm], 0, 0, 0);
            }
        }
        __builtin_amdgcn_s_setprio(0);
    }

    __syncthreads();
#pragma unroll
    for (int t = 0; t < 2; t++)
#pragma unroll
        for (int mm = 0; mm < 2; mm++)
#pragma unroll
            for (int r = 0; r < 4; r++)
                osf[mm * 16 + lhi * 4 + r][wv * 32 + t * 16 + llo] = acc[t][mm][r] + bias[mm][r];
    __syncthreads();
#pragma unroll
    for (int p = 0; p < 4; p++) {
        int chl = p * 8 + (tx >> 5);
        float4 v = *(const float4*)&osf[chl][(tx & 31) * 4];
        *(float4*)(out + ((size_t)bb * COUT + chl) * NPIX + y * WW + px0 + (tx & 31) * 4) = v;
    }
}

extern "C" void kernel_launch(void* const* d_in, const int* in_sizes, int n_in,
                              void* d_out, int out_size, void* d_ws, size_t ws_size,
                              hipStream_t stream) {
    const float* x  = (const float*)d_in[0];
    const float* w1 = (const float*)d_in[1];
    const float* b1 = (const float*)d_in[2];
    const float* w2 = (const float*)d_in[3];
    const float* b2 = (const float*)d_in[4];
    float* out = (float*)d_out;

    char* ws = (char*)d_ws;
    float* wts  = (float*)(ws + 4096);
    short* w1t  = (short*)(ws + 69632);
    short* w2te = (short*)(ws + 364544);
    const size_t OFF_XT = 1048576;

    int nb = 4;
    size_t xt_sz = (size_t)nb * PW * 4 * PW * 16;
    size_t pw_sz = (size_t)nb * 512 * 4096 * 2;
    size_t ps_sz = (size_t)nb * 512 * 128 * 4;
    size_t vt_sz = (size_t)nb * 2 * PW * (size_t)VROW * 2;
    if (ws_size < OFF_XT + xt_sz + pw_sz + ps_sz + vt_sz) {
        nb = 1;
        xt_sz = (size_t)nb * PW * 4 * PW * 16;
        pw_sz = (size_t)nb * 512 * 4096 * 2;
        ps_sz = (size_t)nb * 512 * 128 * 4;
        vt_sz = (size_t)nb * 2 * PW * (size_t)VROW * 2;
    }
    const size_t pw_off = OFF_XT + xt_sz;
    const size_t ps_off = pw_off + pw_sz;
    const size_t vt_off = ps_off + ps_sz;

    unsigned short* xt2 = (unsigned short*)(ws + OFF_XT);
    unsigned short* pw  = (unsigned short*)(ws + pw_off);
    float*          psb = (float*)(ws + ps_off);
    unsigned short* vt  = (unsigned short*)(ws + vt_off);

    k_w1t<<<dim3(9), 256, 0, stream>>>(w1, w1t);

    for (int b0 = 0; b0 < B_; b0 += nb) {
        k_xt2  <<<dim3(PW, nb),      256, 0, stream>>>(x, xt2, b0);
        k_bordv<<<dim3(PW, nb * 2),  256, 0, stream>>>(vt);
        k_conv1<<<dim3(2 * HH * nb), 256, 0, stream>>>(xt2, w1t, b1, vt, pw, psb, nb);
        k_wred <<<dim3(nb * 4, 4),   256, 0, stream>>>(pw, psb, wts, b0);
        k_w2e  <<<dim3(nb, 9),       256, 0, stream>>>(w2, wts, w2te, b0);
        k_conv2e<<<dim3(2 * HH * nb),256, 0, stream>>>(vt, w2te, b2, out, b0, nb);
    }
}

// Round 20
// 203.786 us; speedup vs baseline: 1.0550x; 1.0550x over previous
//
#include <hip/hip_runtime.h>
#include <hip/hip_bf16.h>

typedef __hip_bfloat16 bf16;
typedef __attribute__((ext_vector_type(8))) short short8;
typedef __attribute__((ext_vector_type(4))) float f32x4;
typedef __attribute__((ext_vector_type(16))) float f32x16;

#define B_    4
#define CIN   32
#define HH    256
#define WW    256
#define C1    384
#define NPIX  65536
#define CMID  128
#define COUT  32
#define PW    258
#define VROW  16512   // shorts per padded vt row: 8g * 258col * 8ch

static __device__ __forceinline__ float u2f(unsigned short u) {
    unsigned int x = ((unsigned int)u) << 16;
    return __uint_as_float(x);
}
static __device__ __forceinline__ unsigned short f2u(float f) {
    bf16 h = __float2bfloat16(f);
    return __builtin_bit_cast(unsigned short, h);
}
static __device__ __forceinline__ unsigned int pk2(float lo, float hi) {
    return (unsigned int)f2u(lo) | ((unsigned int)f2u(hi) << 16);
}
static __device__ __forceinline__ void gload16(const void* src, void* dst) {
    __builtin_amdgcn_global_load_lds(
        (const __attribute__((address_space(1))) void*)src,
        (__attribute__((address_space(3))) void*)dst, 16, 0, 0);
}

// ---- w1(384,32,3,3) fp32 -> w1t[tap][cihi4][co384][8] bf16 ----
__global__ __launch_bounds__(256) void k_w1t(const float* __restrict__ w1, short* __restrict__ w1t) {
    const int tap = blockIdx.x;
    for (int i = threadIdx.x; i < 384 * 32; i += 256) {
        int co = i >> 5, cij = i & 31;
        w1t[((size_t)(tap * 4 + (cij >> 3)) * 384 + co) * 8 + (cij & 7)] =
            (short)f2u(w1[(size_t)i * 9 + tap]);
    }
}

// ---- x -> xt2[bl][row][cihi4][col PW][8ch] bf16, zero-padded ----
__global__ __launch_bounds__(256) void k_xt2(const float* __restrict__ x,
                                             unsigned short* __restrict__ xt2, int b0) {
    const int row = blockIdx.x, bl = blockIdx.y, b = b0 + bl;
    const int tx = threadIdx.x;
    unsigned short* rbase = xt2 + (size_t)(bl * PW + row) * 4 * PW * 8;
    const uint4 z = make_uint4(0u, 0u, 0u, 0u);
    if (row == 0 || row == PW - 1) {
        for (int i = tx; i < 4 * PW; i += 256) ((uint4*)rbase)[i] = z;
        return;
    }
    if (tx < 2) {
        int c = tx ? (PW - 1) : 0;
#pragma unroll
        for (int ch = 0; ch < 4; ch++)
            *(uint4*)(rbase + ((size_t)ch * PW + c) * 8) = z;
    }
    const int col = tx + 1;
    const size_t px = (size_t)(row - 1) * WW + tx;
    unsigned int pk[16];
#pragma unroll
    for (int c2 = 0; c2 < 16; c2++) {
        float v0 = x[((size_t)b * CIN + 2 * c2) * NPIX + px];
        float v1 = x[((size_t)b * CIN + 2 * c2 + 1) * NPIX + px];
        pk[c2] = pk2(v0, v1);
    }
#pragma unroll
    for (int ch = 0; ch < 4; ch++)
        *(uint4*)(rbase + ((size_t)ch * PW + col) * 8) =
            make_uint4(pk[ch * 4], pk[ch * 4 + 1], pk[ch * 4 + 2], pk[ch * 4 + 3]);
}

// ---- zero vt borders ----
__global__ __launch_bounds__(256) void k_bordv(unsigned short* __restrict__ vt) {
    const int row = blockIdx.x, bp = blockIdx.y, tx = threadIdx.x;
    unsigned short* base = vt + ((size_t)bp * PW + row) * VROW;
    const uint4 z = make_uint4(0u, 0u, 0u, 0u);
    if (row == 0 || row == PW - 1) {
        for (int i = tx; i < VROW / 8; i += 256) ((uint4*)base)[i] = z;
    } else if (tx < 16) {
        int g = tx >> 1, c = (tx & 1) * (PW - 1);
        *(uint4*)(base + ((size_t)g * PW + c) * 8) = z;
    }
}

// ---- conv1 FUSED, double-buffered epilogue tile (r16 structure, no setprio) ----
// LDS: xs 25344 + 2*17408 = 60160 B -> 2 blocks/CU
__global__ __launch_bounds__(256, 2) void k_conv1(
    const unsigned short* __restrict__ xt2, const short* __restrict__ w1t,
    const float* __restrict__ b1, unsigned short* __restrict__ vt,
    unsigned short* __restrict__ pw, float* __restrict__ ps, int nb)
{
    const int nblk = 512 * nb;
    const int m = ((int)blockIdx.x & 7) * (nblk >> 3) + ((int)blockIdx.x >> 3);
    const int chunk = m & 1;
    const int y   = (m >> 1) & 255;
    const int bl  = m >> 9;
    const int px0 = chunk * 128;
    const int cid = bl * 512 + y * 2 + chunk;
    const int tx  = threadIdx.x;
    const int wv  = tx >> 6, l = tx & 63;
    const int lhi = l >> 4, llo = l & 15;

    __shared__ short xs[12 * 132 * 8];
    union obuf {
        short os[64][136];
        short ost[128][66];
        short osw[4][32][32];
    };
    __shared__ obuf ou2[2];

#pragma unroll
    for (int i = 0; i < 3; i++) {
        int p = wv * 3 + i;
        int r = p >> 2, ch = p & 3;
        const char* src = (const char*)xt2 +
            (((size_t)(bl * PW) + y + r) * 4 + ch) * (PW * 16) + (size_t)px0 * 16 + (size_t)l * 16;
        char* dst = (char*)xs + p * 2112;
        gload16(src, dst);
        gload16(src + 1024, dst + 1024);
        if (l < 2) gload16(src + 2048, dst + 2048);
    }
    __syncthreads();

    const short* wbase = w1t + ((size_t)lhi * 384 + llo) * 8;

    short8 qa[2][4];
    f32x4 wacc[2][2];
#pragma unroll
    for (int dt = 0; dt < 2; dt++)
#pragma unroll
        for (int et = 0; et < 2; et++) wacc[dt][et] = (f32x4){0.f, 0.f, 0.f, 0.f};
    float se0 = 0.f, se1 = 0.f;

#pragma unroll
    for (int cog = 0; cog < 6; cog++) {
        const int co0 = cog * 64;
        const int p   = cog & 1;

        f32x4 acc[2][4];
#pragma unroll
        for (int t = 0; t < 2; t++)
#pragma unroll
            for (int mc = 0; mc < 4; mc++) acc[t][mc] = (f32x4){0.f, 0.f, 0.f, 0.f};

        short8 a[4], an[4];
#pragma unroll
        for (int mc = 0; mc < 4; mc++)
            an[mc] = *(const short8*)(wbase + ((size_t)co0 + mc * 16) * 8);
#pragma unroll
        for (int tap = 0; tap < 9; tap++) {
            const int dy = tap / 3, dx = tap % 3;
#pragma unroll
            for (int mc = 0; mc < 4; mc++) a[mc] = an[mc];
            if (tap < 8) {
#pragma unroll
                for (int mc = 0; mc < 4; mc++)
                    an[mc] = *(const short8*)(wbase +
                        ((size_t)(tap + 1) * 4 * 384 + co0 + mc * 16) * 8);
            }
#pragma unroll
            for (int t = 0; t < 2; t++) {
                short8 bfr = *(const short8*)&xs[(((dy * 4 + lhi) * 132) + (wv * 32 + t * 16 + llo + dx)) * 8];
#pragma unroll
                for (int mc = 0; mc < 4; mc++)
                    acc[t][mc] = __builtin_amdgcn_mfma_f32_16x16x32_bf16(a[mc], bfr, acc[t][mc], 0, 0, 0);
            }
        }

        float bias[4][4];
#pragma unroll
        for (int mc = 0; mc < 4; mc++)
#pragma unroll
            for (int r = 0; r < 4; r++)
                bias[mc][r] = b1[co0 + mc * 16 + lhi * 4 + r];

        if (cog < 4) {     // q,k: channel-major staging (alternating buffer)
#pragma unroll
            for (int t = 0; t < 2; t++)
#pragma unroll
                for (int mc = 0; mc < 4; mc++)
#pragma unroll
                    for (int r = 0; r < 4; r++)
                        ou2[p].os[mc * 16 + lhi * 4 + r][wv * 32 + t * 16 + llo] =
                            (short)f2u(acc[t][mc][r] + bias[mc][r]);
        } else {           // v: transposed [px][ch] staging
#pragma unroll
            for (int t = 0; t < 2; t++)
#pragma unroll
                for (int mc = 0; mc < 4; mc++)
#pragma unroll
                    for (int r = 0; r < 4; r++)
                        ou2[p].ost[wv * 32 + t * 16 + llo][mc * 16 + lhi * 4 + r] =
                            (short)f2u(acc[t][mc][r] + bias[mc][r]);
        }
        __syncthreads();   // ou2[p] visible (single barrier per cog)

        if (cog < 2) {
            if ((wv >> 1) == cog) {
                const int chb = (wv & 1) * 32;
#pragma unroll
                for (int dt = 0; dt < 2; dt++)
#pragma unroll
                    for (int ks = 0; ks < 4; ks++)
                        qa[dt][ks] = *(const short8*)&ou2[p].os[chb + dt * 16 + llo][ks * 32 + lhi * 8];
            }
        } else if (cog < 4) {
            if ((wv >> 1) == cog - 2) {
                const int chb = (wv & 1) * 32;
#pragma unroll
                for (int et = 0; et < 2; et++)
#pragma unroll
                    for (int ks = 0; ks < 4; ks++) {
                        short8 kf = *(const short8*)&ou2[p].os[chb + et * 16 + llo][ks * 32 + lhi * 8];
                        short8 pf;
#pragma unroll
                        for (int j = 0; j < 8; j++) {
                            float ef = __expf(u2f((unsigned short)kf[j]));
                            if (et == 0) se0 += ef; else se1 += ef;
                            pf[j] = (short)f2u(ef);
                        }
#pragma unroll
                        for (int dt = 0; dt < 2; dt++)
                            wacc[dt][et] = __builtin_amdgcn_mfma_f32_16x16x32_bf16(
                                qa[dt][ks], pf, wacc[dt][et], 0, 0, 0);
                    }
            }
        } else {
            const int plane = cog - 4;
            unsigned short* rowb = vt + ((size_t)(bl * 2 + plane) * PW + 1 + y) * VROW;
#pragma unroll
            for (int i = 0; i < 4; i++) {
                int u = i * 256 + tx;
                int g = u >> 7, px = u & 127;
                uint4 v = *(const uint4*)&ou2[p].ost[px][g * 8];
                *(uint4*)(rowb + ((size_t)g * PW + 1 + px0 + px) * 8) = v;
            }
        }
    }

    se0 += __shfl_xor(se0, 16); se0 += __shfl_xor(se0, 32);
    se1 += __shfl_xor(se1, 16); se1 += __shfl_xor(se1, 32);
    if (l < 16) {
        ps[(size_t)cid * 128 + wv * 32 + llo]      = se0;
        ps[(size_t)cid * 128 + wv * 32 + 16 + llo] = se1;
    }

    // weights epilogue into ou2[0] (cog4's readers finished before cog5's barrier)
#pragma unroll
    for (int dt = 0; dt < 2; dt++)
#pragma unroll
        for (int et = 0; et < 2; et++)
#pragma unroll
            for (int r = 0; r < 4; r++)
                ou2[0].osw[wv][dt * 16 + lhi * 4 + r][et * 16 + llo] = (short)f2u(wacc[dt][et][r]);
    __syncthreads();

    {
        unsigned short* pwp = pw + (size_t)cid * 4096;
        const unsigned short* osf = (const unsigned short*)&ou2[0];
#pragma unroll
        for (int p2 = 0; p2 < 2; p2++)
            *(uint4*)(pwp + p2 * 2048 + tx * 8) = *(const uint4*)(osf + p2 * 2048 + tx * 8);
    }
}

// ---- reduce partials over 512 chunks (pw bf16), unrolled for MLP ----
__global__ __launch_bounds__(256) void k_wred(
    const unsigned short* __restrict__ pw, const float* __restrict__ ps,
    float* __restrict__ wts, int b0)
{
    const int bh = blockIdx.x;
    const int jq = blockIdx.y;
    const int bl = bh >> 2, h = bh & 3;
    const int tx = threadIdx.x;
    __shared__ float rinvs[32];
    if (tx < 32) {
        float s = 0.f;
        const float* pp = ps + (size_t)bl * 512 * 128 + h * 32 + tx;
#pragma unroll 8
        for (int c = 0; c < 512; c++) s += pp[(size_t)c * 128];
        rinvs[tx] = 1.f / s;
    }
    __syncthreads();
    const int i = jq * 256 + tx;
    const unsigned short* pwp = pw + (size_t)bl * 512 * 4096 + h * 1024 + i;
    float s = 0.f;
#pragma unroll 8
    for (int c = 0; c < 512; c++) s += u2f(pwp[(size_t)c * 4096]);
    wts[(size_t)(b0 * 4 + bh) * 1024 + i] = s * rinvs[i & 31];
}

// ---- fold W into w2: w2te[bl][tap][cvhi16][co32][8] bf16 ----
__global__ __launch_bounds__(256) void k_w2e(
    const float* __restrict__ w2, const float* __restrict__ wts,
    short* __restrict__ w2te, int b0)
{
    const int bl = blockIdx.x, tap = blockIdx.y;
    const int tx = threadIdx.x;
    __shared__ float Wsh[4096];
    __shared__ float w2sh[4096];
    for (int i = tx; i < 4096; i += 256) {
        Wsh[i]  = wts[(size_t)(b0 + bl) * 4096 + i];
        w2sh[i] = w2[(size_t)i * 9 + tap];
    }
    __syncthreads();
#pragma unroll
    for (int rep = 0; rep < 16; rep++) {
        int o = rep * 256 + tx;
        int cv = o >> 5, co = o & 31;
        int h = cv >> 5, d = cv & 31;
        const float* wp = &w2sh[co * 128 + 32 * h];
        const float* Wp = &Wsh[h * 1024 + d * 32];
        float s = 0.f;
#pragma unroll
        for (int e = 0; e < 32; e++) s += wp[e] * Wp[e];
        w2te[((((size_t)bl * 9 + tap) * 16 + (cv >> 3)) * 32 + co) * 8 + (cv & 7)] =
            (short)f2u(s);
    }
}

// ---- conv2e: prefetch-pipelined implicit GEMM (double-buffered xs, no setprio) ----
__global__ __launch_bounds__(256, 2) void k_conv2e(
    const unsigned short* __restrict__ vt, const short* __restrict__ w2te,
    const float* __restrict__ b2, float* __restrict__ out, int b0, int nb)
{
    const int nblk = 512 * nb;
    const int m = ((int)blockIdx.x & 7) * (nblk >> 3) + ((int)blockIdx.x >> 3);
    const int chunk = m & 1;
    const int y   = (m >> 1) & 255;
    const int bl  = m >> 9;
    const int px0 = chunk * 128;
    const int bb  = b0 + bl;
    const int tx  = threadIdx.x;
    const int wv  = tx >> 6, l = tx & 63;
    const int lhi = l >> 4, llo = l & 15;

    __shared__ short xs2[2][12 * 132 * 8];
    __shared__ float osf[32][132];

    const short* w2b = w2te + (size_t)bl * 9 * 16 * 32 * 8;

    float bias[2][4];
#pragma unroll
    for (int mm = 0; mm < 2; mm++)
#pragma unroll
        for (int r = 0; r < 4; r++)
            bias[mm][r] = b2[mm * 16 + lhi * 4 + r];

    f32x4 acc[2][2];
#pragma unroll
    for (int t = 0; t < 2; t++)
#pragma unroll
        for (int mm = 0; mm < 2; mm++) acc[t][mm] = (f32x4){0.f, 0.f, 0.f, 0.f};

#pragma unroll
    for (int i = 0; i < 3; i++) {
        int p = wv * 3 + i;
        int r = p >> 2, sg = p & 3;
        const char* src = (const char*)vt +
            (((size_t)(bl * 2 + 0) * PW + y + r) * VROW
             + ((size_t)(0 * 4 + sg) * PW + px0) * 8) * 2 + (size_t)l * 16;
        char* dst = (char*)xs2[0] + p * 2112;
        gload16(src, dst);
        gload16(src + 1024, dst + 1024);
        if (l < 2) gload16(src + 2048, dst + 2048);
    }

#pragma unroll
    for (int cc = 0; cc < 4; cc++) {
        __syncthreads();

        if (cc < 3) {
            const int nplane = (cc + 1) >> 1, nghalf = (cc + 1) & 1;
#pragma unroll
            for (int i = 0; i < 3; i++) {
                int p = wv * 3 + i;
                int r = p >> 2, sg = p & 3;
                const char* src = (const char*)vt +
                    (((size_t)(bl * 2 + nplane) * PW + y + r) * VROW
                     + ((size_t)(nghalf * 4 + sg) * PW + px0) * 8) * 2 + (size_t)l * 16;
                char* dst = (char*)xs2[(cc + 1) & 1] + p * 2112;
                gload16(src, dst);
                gload16(src + 1024, dst + 1024);
                if (l < 2) gload16(src + 2048, dst + 2048);
            }
        }

        const short* xsc = xs2[cc & 1];
        short8 a[2], an[2];
#pragma unroll
        for (int mm = 0; mm < 2; mm++)
            an[mm] = *(const short8*)(w2b + ((size_t)(cc * 4 + lhi) * 32 + mm * 16 + llo) * 8);
#pragma unroll
        for (int tap = 0; tap < 9; tap++) {
            const int dy = tap / 3, dx = tap % 3;
#pragma unroll
            for (int mm = 0; mm < 2; mm++) a[mm] = an[mm];
            if (tap < 8) {
#pragma unroll
                for (int mm = 0; mm < 2; mm++)
                    an[mm] = *(const short8*)(w2b +
                        ((size_t)((tap + 1) * 16 + cc * 4 + lhi) * 32 + mm * 16 + llo) * 8);
            }
#pragma unroll
            for (int t = 0; t < 2; t++) {
                short8 bfr = *(const short8*)&xsc[(((dy * 4 + lhi) * 132) + (wv * 32 + t * 16 + llo + dx)) * 8];
#pragma unroll
                for (int mm = 0; mm < 2; mm++)
                    acc[t][mm] = __builtin_amdgcn_mfma_f32_16x16x32_bf16(a[mm], bfr, acc[t][mm], 0, 0, 0);
            }
        }
    }

    __syncthreads();
#pragma unroll
    for (int t = 0; t < 2; t++)
#pragma unroll
        for (int mm = 0; mm < 2; mm++)
#pragma unroll
            for (int r = 0; r < 4; r++)
                osf[mm * 16 + lhi * 4 + r][wv * 32 + t * 16 + llo] = acc[t][mm][r] + bias[mm][r];
    __syncthreads();
#pragma unroll
    for (int p = 0; p < 4; p++) {
        int chl = p * 8 + (tx >> 5);
        float4 v = *(const float4*)&osf[chl][(tx & 31) * 4];
        *(float4*)(out + ((size_t)bb * COUT + chl) * NPIX + y * WW + px0 + (tx & 31) * 4) = v;
    }
}

extern "C" void kernel_launch(void* const* d_in, const int* in_sizes, int n_in,
                              void* d_out, int out_size, void* d_ws, size_t ws_size,
                              hipStream_t stream) {
    const float* x  = (const float*)d_in[0];
    const float* w1 = (const float*)d_in[1];
    const float* b1 = (const float*)d_in[2];
    const float* w2 = (const float*)d_in[3];
    const float* b2 = (const float*)d_in[4];
    float* out = (float*)d_out;

    char* ws = (char*)d_ws;
    float* wts  = (float*)(ws + 4096);
    short* w1t  = (short*)(ws + 69632);
    short* w2te = (short*)(ws + 364544);
    const size_t OFF_XT = 1048576;

    int nb = 4;
    size_t xt_sz = (size_t)nb * PW * 4 * PW * 16;
    size_t pw_sz = (size_t)nb * 512 * 4096 * 2;
    size_t ps_sz = (size_t)nb * 512 * 128 * 4;
    size_t vt_sz = (size_t)nb * 2 * PW * (size_t)VROW * 2;
    if (ws_size < OFF_XT + xt_sz + pw_sz + ps_sz + vt_sz) {
        nb = 1;
        xt_sz = (size_t)nb * PW * 4 * PW * 16;
        pw_sz = (size_t)nb * 512 * 4096 * 2;
        ps_sz = (size_t)nb * 512 * 128 * 4;
        vt_sz = (size_t)nb * 2 * PW * (size_t)VROW * 2;
    }
    const size_t pw_off = OFF_XT + xt_sz;
    const size_t ps_off = pw_off + pw_sz;
    const size_t vt_off = ps_off + ps_sz;

    unsigned short* xt2 = (unsigned short*)(ws + OFF_XT);
    unsigned short* pw  = (unsigned short*)(ws + pw_off);
    float*          psb = (float*)(ws + ps_off);
    unsigned short* vt  = (unsigned short*)(ws + vt_off);

    k_w1t<<<dim3(9), 256, 0, stream>>>(w1, w1t);

    for (int b0 = 0; b0 < B_; b0 += nb) {
        k_xt2  <<<dim3(PW, nb),      256, 0, stream>>>(x, xt2, b0);
        k_bordv<<<dim3(PW, nb * 2),  256, 0, stream>>>(vt);
        k_conv1<<<dim3(2 * HH * nb), 256, 0, stream>>>(xt2, w1t, b1, vt, pw, psb, nb);
        k_wred <<<dim3(nb * 4, 4),   256, 0, stream>>>(pw, psb, wts, b0);
        k_w2e  <<<dim3(nb, 9),       256, 0, stream>>>(w2, wts, w2te, b0);
        k_conv2e<<<dim3(2 * HH * nb),256, 0, stream>>>(vt, w2te, b2, out, b0, nb);
    }
}

// Round 21
// 181.529 us; speedup vs baseline: 1.1843x; 1.1226x over previous
//
#include <hip/hip_runtime.h>
#include <hip/hip_bf16.h>

typedef __hip_bfloat16 bf16;
typedef __attribute__((ext_vector_type(8))) short short8;
typedef __attribute__((ext_vector_type(4))) float f32x4;
typedef __attribute__((ext_vector_type(16))) float f32x16;

#define B_    4
#define CIN   32
#define HH    256
#define WW    256
#define C1    384
#define NPIX  65536
#define CMID  128
#define COUT  32
#define PW    258
#define VROW  16512   // shorts per padded vt row: 8g * 258col * 8ch

static __device__ __forceinline__ float u2f(unsigned short u) {
    unsigned int x = ((unsigned int)u) << 16;
    return __uint_as_float(x);
}
static __device__ __forceinline__ unsigned short f2u(float f) {
    bf16 h = __float2bfloat16(f);
    return __builtin_bit_cast(unsigned short, h);
}
static __device__ __forceinline__ unsigned int pk2(float lo, float hi) {
    return (unsigned int)f2u(lo) | ((unsigned int)f2u(hi) << 16);
}
static __device__ __forceinline__ void gload16(const void* src, void* dst) {
    __builtin_amdgcn_global_load_lds(
        (const __attribute__((address_space(1))) void*)src,
        (__attribute__((address_space(3))) void*)dst, 16, 0, 0);
}

// ---- w1(384,32,3,3) fp32 -> w1t[tap][cihi4][co384][8] bf16 ----
__global__ __launch_bounds__(256) void k_w1t(const float* __restrict__ w1, short* __restrict__ w1t) {
    const int tap = blockIdx.x;
    for (int i = threadIdx.x; i < 384 * 32; i += 256) {
        int co = i >> 5, cij = i & 31;
        w1t[((size_t)(tap * 4 + (cij >> 3)) * 384 + co) * 8 + (cij & 7)] =
            (short)f2u(w1[(size_t)i * 9 + tap]);
    }
}

// ---- prepass: xt2 transpose (by<nb) + vt border zero (by>=nb); grid (PW, 3*nb) ----
__global__ __launch_bounds__(256) void k_prep(const float* __restrict__ x,
                                              unsigned short* __restrict__ xt2,
                                              unsigned short* __restrict__ vt,
                                              int b0, int nb) {
    const int row = blockIdx.x, by = blockIdx.y, tx = threadIdx.x;
    const uint4 z = make_uint4(0u, 0u, 0u, 0u);
    if (by >= nb) {   // vt border zero, bp = by-nb in [0, 2nb)
        const int bp = by - nb;
        unsigned short* base = vt + ((size_t)bp * PW + row) * VROW;
        if (row == 0 || row == PW - 1) {
            for (int i = tx; i < VROW / 8; i += 256) ((uint4*)base)[i] = z;
        } else if (tx < 16) {
            int g = tx >> 1, c = (tx & 1) * (PW - 1);
            *(uint4*)(base + ((size_t)g * PW + c) * 8) = z;
        }
        return;
    }
    const int bl = by, b = b0 + bl;
    unsigned short* rbase = xt2 + (size_t)(bl * PW + row) * 4 * PW * 8;
    if (row == 0 || row == PW - 1) {
        for (int i = tx; i < 4 * PW; i += 256) ((uint4*)rbase)[i] = z;
        return;
    }
    if (tx < 2) {
        int c = tx ? (PW - 1) : 0;
#pragma unroll
        for (int ch = 0; ch < 4; ch++)
            *(uint4*)(rbase + ((size_t)ch * PW + c) * 8) = z;
    }
    const int col = tx + 1;
    const size_t px = (size_t)(row - 1) * WW + tx;
    unsigned int pk[16];
#pragma unroll
    for (int c2 = 0; c2 < 16; c2++) {
        float v0 = x[((size_t)b * CIN + 2 * c2) * NPIX + px];
        float v1 = x[((size_t)b * CIN + 2 * c2 + 1) * NPIX + px];
        pk[c2] = pk2(v0, v1);
    }
#pragma unroll
    for (int ch = 0; ch < 4; ch++)
        *(uint4*)(rbase + ((size_t)ch * PW + col) * 8) =
            make_uint4(pk[ch * 4], pk[ch * 4 + 1], pk[ch * 4 + 2], pk[ch * 4 + 3]);
}

// ---- conv1 FUSED, FULL-ROW blocks (256 px) — r17 best-total configuration ----
// grid 256*nb. LDS: xs 49536 + ou 17408 = 66944 B -> 2 blocks/CU
__global__ __launch_bounds__(256, 2) void k_conv1(
    const unsigned short* __restrict__ xt2, const short* __restrict__ w1t,
    const float* __restrict__ b1, unsigned short* __restrict__ vt,
    unsigned short* __restrict__ pw, float* __restrict__ ps, int nb)
{
    const int nblk = 256 * nb;
    const int m = ((int)blockIdx.x & 7) * (nblk >> 3) + ((int)blockIdx.x >> 3);
    const int y   = m & 255;
    const int bl  = m >> 8;
    const int cid = bl * 256 + y;
    const int tx  = threadIdx.x;
    const int wv  = tx >> 6, l = tx & 63;
    const int lhi = l >> 4, llo = l & 15;

    __shared__ short xs[12 * 258 * 8];          // full row + halo
    __shared__ union {
        short os[64][136];
        short ost[128][66];
        short osw[4][32][32];
    } ou;

    // stage full row: 12 (r,ch) segs of 258 cols (4128 B each)
#pragma unroll
    for (int i = 0; i < 3; i++) {
        int p = wv * 3 + i;
        int r = p >> 2, ch = p & 3;
        const char* src = (const char*)xt2 +
            (((size_t)(bl * PW) + y + r) * 4 + ch) * (PW * 16) + (size_t)l * 16;
        char* dst = (char*)xs + p * 4128;
        gload16(src, dst);
        gload16(src + 1024, dst + 1024);
        gload16(src + 2048, dst + 2048);
        gload16(src + 3072, dst + 3072);
        if (l < 2) gload16(src + 4096, dst + 4096);
    }
    __syncthreads();

    const short* wbase = w1t + ((size_t)lhi * 384 + llo) * 8;

    short8 qa[2][8];          // q A-frags [dtile][kstep 0..7], K=256
    f32x4 wacc[2][2];
#pragma unroll
    for (int dt = 0; dt < 2; dt++)
#pragma unroll
        for (int et = 0; et < 2; et++) wacc[dt][et] = (f32x4){0.f, 0.f, 0.f, 0.f};
    float se0 = 0.f, se1 = 0.f;

#pragma unroll
    for (int cog = 0; cog < 6; cog++) {
        const int co0 = cog * 64;

        f32x4 acc[4][4];      // [ttile][cotile]
#pragma unroll
        for (int t = 0; t < 4; t++)
#pragma unroll
            for (int mc = 0; mc < 4; mc++) acc[t][mc] = (f32x4){0.f, 0.f, 0.f, 0.f};

        short8 a[4], an[4];
#pragma unroll
        for (int mc = 0; mc < 4; mc++)
            an[mc] = *(const short8*)(wbase + ((size_t)co0 + mc * 16) * 8);
#pragma unroll
        for (int tap = 0; tap < 9; tap++) {
            const int dy = tap / 3, dx = tap % 3;
#pragma unroll
            for (int mc = 0; mc < 4; mc++) a[mc] = an[mc];
            if (tap < 8) {
#pragma unroll
                for (int mc = 0; mc < 4; mc++)
                    an[mc] = *(const short8*)(wbase +
                        ((size_t)(tap + 1) * 4 * 384 + co0 + mc * 16) * 8);
            }
#pragma unroll
            for (int t = 0; t < 4; t++) {
                short8 bfr = *(const short8*)&xs[(((dy * 4 + lhi) * 258) + (wv * 64 + t * 16 + llo + dx)) * 8];
#pragma unroll
                for (int mc = 0; mc < 4; mc++)
                    acc[t][mc] = __builtin_amdgcn_mfma_f32_16x16x32_bf16(a[mc], bfr, acc[t][mc], 0, 0, 0);
            }
        }

        float bias[4][4];
#pragma unroll
        for (int mc = 0; mc < 4; mc++)
#pragma unroll
            for (int r = 0; r < 4; r++)
                bias[mc][r] = b1[co0 + mc * 16 + lhi * 4 + r];

        // two 128-px sub-phases through the single ou tile
#pragma unroll
        for (int h2 = 0; h2 < 2; h2++) {
            __syncthreads();   // previous consume done / ou free
            if ((wv >> 1) == h2) {
                const int pxl0 = (wv & 1) * 64;
                if (cog < 4) {
#pragma unroll
                    for (int t = 0; t < 4; t++)
#pragma unroll
                        for (int mc = 0; mc < 4; mc++)
#pragma unroll
                            for (int r = 0; r < 4; r++)
                                ou.os[mc * 16 + lhi * 4 + r][pxl0 + t * 16 + llo] =
                                    (short)f2u(acc[t][mc][r] + bias[mc][r]);
                } else {
#pragma unroll
                    for (int t = 0; t < 4; t++)
#pragma unroll
                        for (int mc = 0; mc < 4; mc++)
#pragma unroll
                            for (int r = 0; r < 4; r++)
                                ou.ost[pxl0 + t * 16 + llo][mc * 16 + lhi * 4 + r] =
                                    (short)f2u(acc[t][mc][r] + bias[mc][r]);
                }
            }
            __syncthreads();   // ou visible

            if (cog < 2) {
                if ((wv >> 1) == cog) {
                    const int chb = (wv & 1) * 32;
#pragma unroll
                    for (int dt = 0; dt < 2; dt++)
#pragma unroll
                        for (int ks = 0; ks < 4; ks++)
                            qa[dt][h2 * 4 + ks] =
                                *(const short8*)&ou.os[chb + dt * 16 + llo][ks * 32 + lhi * 8];
                }
            } else if (cog < 4) {
                if ((wv >> 1) == cog - 2) {
                    const int chb = (wv & 1) * 32;
#pragma unroll
                    for (int et = 0; et < 2; et++)
#pragma unroll
                        for (int ks = 0; ks < 4; ks++) {
                            short8 kf = *(const short8*)&ou.os[chb + et * 16 + llo][ks * 32 + lhi * 8];
                            short8 pf;
#pragma unroll
                            for (int j = 0; j < 8; j++) {
                                float ef = __expf(u2f((unsigned short)kf[j]));
                                if (et == 0) se0 += ef; else se1 += ef;
                                pf[j] = (short)f2u(ef);
                            }
#pragma unroll
                            for (int dt = 0; dt < 2; dt++)
                                wacc[dt][et] = __builtin_amdgcn_mfma_f32_16x16x32_bf16(
                                    qa[dt][h2 * 4 + ks], pf, wacc[dt][et], 0, 0, 0);
                        }
                }
            } else {
                const int plane = cog - 4;
                unsigned short* rowb = vt + ((size_t)(bl * 2 + plane) * PW + 1 + y) * VROW;
#pragma unroll
                for (int i = 0; i < 4; i++) {
                    int u = i * 256 + tx;
                    int g = u >> 7, px = u & 127;
                    uint4 v = *(const uint4*)&ou.ost[px][g * 8];
                    *(uint4*)(rowb + ((size_t)g * PW + 1 + h2 * 128 + px) * 8) = v;
                }
            }
        }
    }

    se0 += __shfl_xor(se0, 16); se0 += __shfl_xor(se0, 32);
    se1 += __shfl_xor(se1, 16); se1 += __shfl_xor(se1, 32);
    if (l < 16) {
        ps[(size_t)cid * 128 + wv * 32 + llo]      = se0;
        ps[(size_t)cid * 128 + wv * 32 + 16 + llo] = se1;
    }

    __syncthreads();   // last consume done
#pragma unroll
    for (int dt = 0; dt < 2; dt++)
#pragma unroll
        for (int et = 0; et < 2; et++)
#pragma unroll
            for (int r = 0; r < 4; r++)
                ou.osw[wv][dt * 16 + lhi * 4 + r][et * 16 + llo] = (short)f2u(wacc[dt][et][r]);
    __syncthreads();

    {
        unsigned short* pwp = pw + (size_t)cid * 4096;
        const unsigned short* osf = (const unsigned short*)&ou;
#pragma unroll
        for (int p2 = 0; p2 < 2; p2++)
            *(uint4*)(pwp + p2 * 2048 + tx * 8) = *(const uint4*)(osf + p2 * 2048 + tx * 8);
    }
}

// ---- reduce partials over 256 rows (pw bf16) ----
__global__ __launch_bounds__(256) void k_wred(
    const unsigned short* __restrict__ pw, const float* __restrict__ ps,
    float* __restrict__ wts, int b0)
{
    const int bh = blockIdx.x;
    const int jq = blockIdx.y;
    const int bl = bh >> 2, h = bh & 3;
    const int tx = threadIdx.x;
    __shared__ float rinvs[32];
    if (tx < 32) {
        float s = 0.f;
        const float* pp = ps + (size_t)bl * 256 * 128 + h * 32 + tx;
        for (int c = 0; c < 256; c++) s += pp[(size_t)c * 128];
        rinvs[tx] = 1.f / s;
    }
    __syncthreads();
    const int i = jq * 256 + tx;
    const unsigned short* pwp = pw + (size_t)bl * 256 * 4096 + h * 1024 + i;
    float s = 0.f;
    for (int c = 0; c < 256; c++) s += u2f(pwp[(size_t)c * 4096]);
    wts[(size_t)(b0 * 4 + bh) * 1024 + i] = s * rinvs[i & 31];
}

// ---- fold W into w2: w2te[bl][tap][cvhi16][co32][8] bf16 ----
__global__ __launch_bounds__(256) void k_w2e(
    const float* __restrict__ w2, const float* __restrict__ wts,
    short* __restrict__ w2te, int b0)
{
    const int bl = blockIdx.x, tap = blockIdx.y;
    const int tx = threadIdx.x;
    __shared__ float Wsh[4096];
    __shared__ float w2sh[4096];
    for (int i = tx; i < 4096; i += 256) {
        Wsh[i]  = wts[(size_t)(b0 + bl) * 4096 + i];
        w2sh[i] = w2[(size_t)i * 9 + tap];
    }
    __syncthreads();
#pragma unroll
    for (int rep = 0; rep < 16; rep++) {
        int o = rep * 256 + tx;
        int cv = o >> 5, co = o & 31;
        int h = cv >> 5, d = cv & 31;
        const float* wp = &w2sh[co * 128 + 32 * h];
        const float* Wp = &Wsh[h * 1024 + d * 32];
        float s = 0.f;
#pragma unroll
        for (int e = 0; e < 32; e++) s += wp[e] * Wp[e];
        w2te[((((size_t)bl * 9 + tap) * 16 + (cv >> 3)) * 32 + co) * 8 + (cv & 7)] =
            (short)f2u(s);
    }
}

// ---- conv2e: prefetch-pipelined implicit GEMM (double-buffered xs) ----
__global__ __launch_bounds__(256, 2) void k_conv2e(
    const unsigned short* __restrict__ vt, const short* __restrict__ w2te,
    const float* __restrict__ b2, float* __restrict__ out, int b0, int nb)
{
    const int nblk = 512 * nb;
    const int m = ((int)blockIdx.x & 7) * (nblk >> 3) + ((int)blockIdx.x >> 3);
    const int chunk = m & 1;
    const int y   = (m >> 1) & 255;
    const int bl  = m >> 9;
    const int px0 = chunk * 128;
    const int bb  = b0 + bl;
    const int tx  = threadIdx.x;
    const int wv  = tx >> 6, l = tx & 63;
    const int lhi = l >> 4, llo = l & 15;

    __shared__ short xs2[2][12 * 132 * 8];
    __shared__ float osf[32][132];

    const short* w2b = w2te + (size_t)bl * 9 * 16 * 32 * 8;

    float bias[2][4];
#pragma unroll
    for (int mm = 0; mm < 2; mm++)
#pragma unroll
        for (int r = 0; r < 4; r++)
            bias[mm][r] = b2[mm * 16 + lhi * 4 + r];

    f32x4 acc[2][2];
#pragma unroll
    for (int t = 0; t < 2; t++)
#pragma unroll
        for (int mm = 0; mm < 2; mm++) acc[t][mm] = (f32x4){0.f, 0.f, 0.f, 0.f};

#pragma unroll
    for (int i = 0; i < 3; i++) {
        int p = wv * 3 + i;
        int r = p >> 2, sg = p & 3;
        const char* src = (const char*)vt +
            (((size_t)(bl * 2 + 0) * PW + y + r) * VROW
             + ((size_t)(0 * 4 + sg) * PW + px0) * 8) * 2 + (size_t)l * 16;
        char* dst = (char*)xs2[0] + p * 2112;
        gload16(src, dst);
        gload16(src + 1024, dst + 1024);
        if (l < 2) gload16(src + 2048, dst + 2048);
    }

#pragma unroll
    for (int cc = 0; cc < 4; cc++) {
        __syncthreads();

        if (cc < 3) {
            const int nplane = (cc + 1) >> 1, nghalf = (cc + 1) & 1;
#pragma unroll
            for (int i = 0; i < 3; i++) {
                int p = wv * 3 + i;
                int r = p >> 2, sg = p & 3;
                const char* src = (const char*)vt +
                    (((size_t)(bl * 2 + nplane) * PW + y + r) * VROW
                     + ((size_t)(nghalf * 4 + sg) * PW + px0) * 8) * 2 + (size_t)l * 16;
                char* dst = (char*)xs2[(cc + 1) & 1] + p * 2112;
                gload16(src, dst);
                gload16(src + 1024, dst + 1024);
                if (l < 2) gload16(src + 2048, dst + 2048);
            }
        }

        const short* xsc = xs2[cc & 1];
        short8 a[2], an[2];
#pragma unroll
        for (int mm = 0; mm < 2; mm++)
            an[mm] = *(const short8*)(w2b + ((size_t)(cc * 4 + lhi) * 32 + mm * 16 + llo) * 8);
#pragma unroll
        for (int tap = 0; tap < 9; tap++) {
            const int dy = tap / 3, dx = tap % 3;
#pragma unroll
            for (int mm = 0; mm < 2; mm++) a[mm] = an[mm];
            if (tap < 8) {
#pragma unroll
                for (int mm = 0; mm < 2; mm++)
                    an[mm] = *(const short8*)(w2b +
                        ((size_t)((tap + 1) * 16 + cc * 4 + lhi) * 32 + mm * 16 + llo) * 8);
            }
#pragma unroll
            for (int t = 0; t < 2; t++) {
                short8 bfr = *(const short8*)&xsc[(((dy * 4 + lhi) * 132) + (wv * 32 + t * 16 + llo + dx)) * 8];
#pragma unroll
                for (int mm = 0; mm < 2; mm++)
                    acc[t][mm] = __builtin_amdgcn_mfma_f32_16x16x32_bf16(a[mm], bfr, acc[t][mm], 0, 0, 0);
            }
        }
    }

    __syncthreads();
#pragma unroll
    for (int t = 0; t < 2; t++)
#pragma unroll
        for (int mm = 0; mm < 2; mm++)
#pragma unroll
            for (int r = 0; r < 4; r++)
                osf[mm * 16 + lhi * 4 + r][wv * 32 + t * 16 + llo] = acc[t][mm][r] + bias[mm][r];
    __syncthreads();
#pragma unroll
    for (int p = 0; p < 4; p++) {
        int chl = p * 8 + (tx >> 5);
        float4 v = *(const float4*)&osf[chl][(tx & 31) * 4];
        *(float4*)(out + ((size_t)bb * COUT + chl) * NPIX + y * WW + px0 + (tx & 31) * 4) = v;
    }
}

extern "C" void kernel_launch(void* const* d_in, const int* in_sizes, int n_in,
                              void* d_out, int out_size, void* d_ws, size_t ws_size,
                              hipStream_t stream) {
    const float* x  = (const float*)d_in[0];
    const float* w1 = (const float*)d_in[1];
    const float* b1 = (const float*)d_in[2];
    const float* w2 = (const float*)d_in[3];
    const float* b2 = (const float*)d_in[4];
    float* out = (float*)d_out;

    char* ws = (char*)d_ws;
    float* wts  = (float*)(ws + 4096);
    short* w1t  = (short*)(ws + 69632);
    short* w2te = (short*)(ws + 364544);
    const size_t OFF_XT = 1048576;

    int nb = 4;
    size_t xt_sz = (size_t)nb * PW * 4 * PW * 16;
    size_t pw_sz = (size_t)nb * 256 * 4096 * 2;
    size_t ps_sz = (size_t)nb * 256 * 128 * 4;
    size_t vt_sz = (size_t)nb * 2 * PW * (size_t)VROW * 2;
    if (ws_size < OFF_XT + xt_sz + pw_sz + ps_sz + vt_sz) {
        nb = 1;
        xt_sz = (size_t)nb * PW * 4 * PW * 16;
        pw_sz = (size_t)nb * 256 * 4096 * 2;
        ps_sz = (size_t)nb * 256 * 128 * 4;
        vt_sz = (size_t)nb * 2 * PW * (size_t)VROW * 2;
    }
    const size_t pw_off = OFF_XT + xt_sz;
    const size_t ps_off = pw_off + pw_sz;
    const size_t vt_off = ps_off + ps_sz;

    unsigned short* xt2 = (unsigned short*)(ws + OFF_XT);
    unsigned short* pw  = (unsigned short*)(ws + pw_off);
    float*          psb = (float*)(ws + ps_off);
    unsigned short* vt  = (unsigned short*)(ws + vt_off);

    k_w1t<<<dim3(9), 256, 0, stream>>>(w1, w1t);

    for (int b0 = 0; b0 < B_; b0 += nb) {
        k_prep <<<dim3(PW, 3 * nb),  256, 0, stream>>>(x, xt2, vt, b0, nb);
        k_conv1<<<dim3(HH * nb),     256, 0, stream>>>(xt2, w1t, b1, vt, pw, psb, nb);
        k_wred <<<dim3(nb * 4, 4),   256, 0, stream>>>(pw, psb, wts, b0);
        k_w2e  <<<dim3(nb, 9),       256, 0, stream>>>(w2, wts, w2te, b0);
        k_conv2e<<<dim3(2 * HH * nb),256, 0, stream>>>(vt, w2te, b2, out, b0, nb);
    }
}